// Round 1
// baseline (4762.278 us; speedup 1.0000x reference)
//
#include <hip/hip_runtime.h>

// 2-layer LSTM, T=512, B=64, H=512, fp32 in/out, bf16 MFMA compute.
// Round r (0..T): layer0 computes step t=r, layer1 computes step t=r-1
// (software pipeline; one kernel launch per round = the grid-wide sync).

#define T_SEQ 512
#define BATCH 64
#define HID   512

typedef short s16x8 __attribute__((ext_vector_type(8)));
typedef float f32x4 __attribute__((ext_vector_type(4)));

__device__ __forceinline__ short f2bf(float f) {
    unsigned u = __builtin_bit_cast(unsigned, f);
    unsigned r = (u + 0x7fffu + ((u >> 16) & 1u)) >> 16;   // RNE
    return (short)r;
}
__device__ __forceinline__ float sigf(float x) { return 1.0f / (1.0f + __expf(-x)); }
__device__ __forceinline__ float tanhff(float x) { return 2.0f * sigf(2.0f * x) - 1.0f; }

// ---- setup: cast x (fp32) -> bf16 ----
__global__ __launch_bounds__(256) void xcast_kernel(const float* __restrict__ x,
                                                    short* __restrict__ xb) {
    int i = (blockIdx.x * 256 + threadIdx.x) * 8;   // grid sized exactly
    float4 a = *(const float4*)(x + i);
    float4 b = *(const float4*)(x + i + 4);
    s16x8 v;
    v[0]=f2bf(a.x); v[1]=f2bf(a.y); v[2]=f2bf(a.z); v[3]=f2bf(a.w);
    v[4]=f2bf(b.x); v[5]=f2bf(b.y); v[6]=f2bf(b.z); v[7]=f2bf(b.w);
    *(s16x8*)(xb + i) = v;
}

// ---- setup: pack weights into per-lane MFMA B-fragment order (bf16) ----
// flat group fg = ((((l*32+bb)*4 + gate)*32 + ks)*64 + lane); holds 8 bf16:
//   B[k][n] with k = ks*32 + (lane>>4)*8 + i, n = lane&15,
//   column n -> gate-row j' = gate*512 + bb*16 + n,
//   k < 512 -> Wxh[l][j'][k], else Whh[l][j'][k-512].
__global__ __launch_bounds__(256) void wpack_kernel(const float* __restrict__ Wxh,
                                                    const float* __restrict__ Whh,
                                                    short* __restrict__ wp) {
    int fg = blockIdx.x * 256 + threadIdx.x;        // [0, 524288)
    int lane = fg & 63;
    int rest = fg >> 6;
    int ks   = rest & 31; rest >>= 5;
    int gate = rest & 3;  rest >>= 2;
    int bb   = rest & 31;
    int l    = rest >> 5;
    int k0 = ks * 32 + (lane >> 4) * 8;
    int jp = gate * 512 + bb * 16 + (lane & 15);
    const float* src = (k0 < 512) ? (Wxh + ((size_t)(l * 2048 + jp) * 512 + k0))
                                  : (Whh + ((size_t)(l * 2048 + jp) * 512 + (k0 - 512)));
    float4 a = *(const float4*)src;
    float4 b = *(const float4*)(src + 4);
    s16x8 v;
    v[0]=f2bf(a.x); v[1]=f2bf(a.y); v[2]=f2bf(a.z); v[3]=f2bf(a.w);
    v[4]=f2bf(b.x); v[5]=f2bf(b.y); v[6]=f2bf(b.z); v[7]=f2bf(b.w);
    *(s16x8*)(wp + (size_t)fg * 8) = v;
}

// ---- one pipeline round: blocks 0..31 = layer0 (t=r), 32..63 = layer1 (t=r-1) ----
// Block bb covers hidden j in [16*bb, 16*bb+16) x 4 gates (64 gate-columns).
// Wave w = gate w; computes D[64 x 16] over K=1024 via 16x16x32 bf16 MFMA.
__global__ __launch_bounds__(256) void step_kernel(
    const short* __restrict__ xb,     // [T][B][H] bf16
    const short* __restrict__ wp,     // packed weights
    short* __restrict__ hbufs,        // [layer][parity][B][H] bf16
    float* __restrict__ cst,          // [layer][B][H] fp32
    const float* __restrict__ bxh,    // [L][4H]
    const float* __restrict__ bhh,    // [L][4H]
    float* __restrict__ out,          // T*B*H | hT[L,B,H] | cT[L,B,H]
    int r) {
    int l  = blockIdx.x >> 5;
    int bb = blockIdx.x & 31;
    if (l == 0 && r == T_SEQ) return;
    if (l == 1 && r == 0) return;
    int t  = (l == 0) ? r : (r - 1);
    int rp = (r + 1) & 1;             // read parity (state written last round)
    int wpar = r & 1;                 // write parity

    __shared__ short Ash[64 * 264];   // A-chunk [64 rows][256+8 pad] bf16
    __shared__ float gbuf[4 * 64 * 16];

    int tid  = threadIdx.x;
    int wv   = tid >> 6;              // wave = gate
    int lane = tid & 63;

    const short* inp_base  = (l == 0) ? (xb + (size_t)t * BATCH * HID)
                                      : (hbufs + (size_t)(0 * 2 + rp) * BATCH * HID);
    const short* hrec_base = hbufs + (size_t)(l * 2 + rp) * BATCH * HID;

    f32x4 acc[4];
    #pragma unroll
    for (int ms = 0; ms < 4; ++ms) acc[ms] = (f32x4){0.f, 0.f, 0.f, 0.f};

    const short* wp_base = wp + (size_t)((l * 32 + bb) * 4 + wv) * 32 * 64 * 8;

    for (int kc = 0; kc < 4; ++kc) {
        __syncthreads();
        // stage A-chunk: global K cols [kc*256, kc*256+256)
        const short* src_base = (kc < 2) ? inp_base : hrec_base;
        int ccol0 = (kc & 1) * 256;
        #pragma unroll
        for (int g = 0; g < 8; ++g) {
            int flat = tid + 256 * g;         // [0,2048) groups of 8 bf16
            int m  = flat >> 5;
            int cg = flat & 31;
            s16x8 v = *(const s16x8*)(src_base + m * HID + ccol0 + cg * 8);
            *(s16x8*)(&Ash[m * 264 + cg * 8]) = v;
        }
        __syncthreads();
        #pragma unroll
        for (int ksl = 0; ksl < 8; ++ksl) {
            int ks = kc * 8 + ksl;
            s16x8 bfrag = *(const s16x8*)(wp_base + ks * 512 + lane * 8);
            int aoff = ksl * 32 + (lane >> 4) * 8;
            #pragma unroll
            for (int ms = 0; ms < 4; ++ms) {
                s16x8 afrag = *(const s16x8*)(&Ash[(ms * 16 + (lane & 15)) * 264 + aoff]);
                acc[ms] = __builtin_amdgcn_mfma_f32_16x16x32_bf16(afrag, bfrag, acc[ms], 0, 0, 0);
            }
        }
    }

    // D[m][n]: n = lane&15, m = ms*16 + (lane>>4)*4 + q   -> gbuf[gate][m][n]
    #pragma unroll
    for (int ms = 0; ms < 4; ++ms)
        #pragma unroll
        for (int q = 0; q < 4; ++q)
            gbuf[(wv * 64 + ms * 16 + (lane >> 4) * 4 + q) * 16 + (lane & 15)] = acc[ms][q];
    __syncthreads();

    const float* bx = bxh + l * 2048;
    const float* bh = bhh + l * 2048;
    #pragma unroll
    for (int q = 0; q < 4; ++q) {
        int item = tid + 256 * q;             // [0,1024) = 64 m x 16 n
        int m = item >> 4;
        int n = item & 15;
        int j = bb * 16 + n;
        float gi = gbuf[(0 * 64 + m) * 16 + n] + bx[j]        + bh[j];
        float gf = gbuf[(1 * 64 + m) * 16 + n] + bx[512 + j]  + bh[512 + j];
        float gg = gbuf[(2 * 64 + m) * 16 + n] + bx[1024 + j] + bh[1024 + j];
        float go = gbuf[(3 * 64 + m) * 16 + n] + bx[1536 + j] + bh[1536 + j];
        float c_old = cst[(size_t)(l * BATCH + m) * HID + j];
        float c_new = sigf(gf) * c_old + sigf(gi) * tanhff(gg);
        float h = sigf(go) * tanhff(c_new);
        cst[(size_t)(l * BATCH + m) * HID + j] = c_new;
        hbufs[(size_t)(l * 2 + wpar) * BATCH * HID + (size_t)m * HID + j] = f2bf(h);
        if (l == 1) out[(size_t)t * BATCH * HID + (size_t)m * HID + j] = h;
        if (t == T_SEQ - 1) {
            size_t base = (size_t)T_SEQ * BATCH * HID;
            out[base + (size_t)(l * BATCH + m) * HID + j] = h;
            out[base + (size_t)2 * BATCH * HID + (size_t)(l * BATCH + m) * HID + j] = c_new;
        }
    }
}

extern "C" void kernel_launch(void* const* d_in, const int* in_sizes, int n_in,
                              void* d_out, int out_size, void* d_ws, size_t ws_size,
                              hipStream_t stream) {
    const float* x   = (const float*)d_in[0];
    const float* Wxh = (const float*)d_in[1];
    const float* Whh = (const float*)d_in[2];
    const float* bxh = (const float*)d_in[3];
    const float* bhh = (const float*)d_in[4];
    float* out = (float*)d_out;

    char* ws = (char*)d_ws;
    short* xb    = (short*)(ws);                     // 33,554,432 B  (x as bf16)
    short* wpk   = (short*)(ws + 33554432);          //  8,388,608 B  (packed W bf16)
    short* hbufs = (short*)(ws + 41943040);          //    262,144 B  (h state, 2 layers x 2 parity)
    float* cst   = (float*)(ws + 42205184);          //    262,144 B  (c state)
    // total ws use: ~40.5 MB

    // zero h/c state (ws is poisoned 0xAA before every timed launch)
    hipMemsetAsync(ws + 41943040, 0, 524288, stream);

    xcast_kernel<<<dim3(8192), dim3(256), 0, stream>>>(x, xb);
    wpack_kernel<<<dim3(2048), dim3(256), 0, stream>>>(Wxh, Whh, wpk);

    for (int r = 0; r <= T_SEQ; ++r)
        step_kernel<<<dim3(64), dim3(256), 0, stream>>>(xb, wpk, hbufs, cst, bxh, bhh, out, r);
}